// Round 6
// baseline (307.627 us; speedup 1.0000x reference)
//
#include <hip/hip_runtime.h>
#include <cstdint>

#define KNB 16
#define FDIM 64
#define HDIM 128
#define SA 130          // Act row stride in f16 units (65 dwords -> conflict-free)
#define SW 65           // WT row stride in dwords
#define CMAX 20         // candidates per thread (covers segments up to 5120)

typedef unsigned long long ull;
typedef _Float16 f16x8 __attribute__((ext_vector_type(8)));
typedef float    f32x16 __attribute__((ext_vector_type(16)));

__device__ __forceinline__ float selu_f(float x){
    const float a = 1.6732632423543772f, s = 1.0507009873554805f;
    return x > 0.f ? s * x : s * a * expm1f(x);
}

__device__ __forceinline__ unsigned int pack2(float a, float b){
    union { _Float16 h[2]; unsigned int u; } t;
    t.h[0] = (_Float16)a; t.h[1] = (_Float16)b;
    return t.u;
}

__device__ __forceinline__ f16x8 ldfrag(const unsigned int* p, unsigned int di){
    union { unsigned int u[4]; f16x8 v; } t;
    t.u[0] = p[di]; t.u[1] = p[di+1]; t.u[2] = p[di+2]; t.u[3] = p[di+3];
    return t.v;
}

// ---- u64 min-reduce across a wave64, pure-VALU DPP (no LDS pipe) ----
template<int CTRL>
__device__ __forceinline__ void dpp_min_u64(unsigned int& rh, unsigned int& rl){
    unsigned int th = (unsigned int)__builtin_amdgcn_update_dpp(-1, (int)rh, CTRL, 0xF, 0xF, false);
    unsigned int tl = (unsigned int)__builtin_amdgcn_update_dpp(-1, (int)rl, CTRL, 0xF, 0xF, false);
    bool lt = (th < rh) || ((th == rh) && (tl < rl));
    rh = lt ? th : rh;
    rl = lt ? tl : rl;
}

__device__ __forceinline__ ull wave_min_u64(ull m){
    unsigned int rh = (unsigned int)(m >> 32), rl = (unsigned int)m;
    dpp_min_u64<0x111>(rh, rl);   // row_shr:1
    dpp_min_u64<0x112>(rh, rl);   // row_shr:2
    dpp_min_u64<0x114>(rh, rl);   // row_shr:4
    dpp_min_u64<0x118>(rh, rl);   // row_shr:8
    dpp_min_u64<0x142>(rh, rl);   // row_bcast:15
    dpp_min_u64<0x143>(rh, rl);   // row_bcast:31
    unsigned int bh = (unsigned int)__builtin_amdgcn_readlane((int)rh, 63);
    unsigned int bl = (unsigned int)__builtin_amdgcn_readlane((int)rl, 63);
    return (((ull)bh) << 32) | bl;
}

// ---------------------------------------------------------------------------
// Kernel 0: weights -> transposed fp16 (WT[n][k] = W[k][n]).
// ---------------------------------------------------------------------------
__global__ __launch_bounds__(256) void conv_kernel(
    const float* __restrict__ We1, const float* __restrict__ We2,
    const float* __restrict__ Wc1, _Float16* __restrict__ WT)
{
    int id = blockIdx.x * 256 + threadIdx.x;     // 0..49151
    int m  = id >> 14;
    int r  = id & 16383;
    int nn = (r >> 7) & 127;
    int k  = r & 127;
    float v;
    if (m == 0)      v = We1[(k + 1) * 128 + nn];
    else if (m == 1) v = We2[k * 128 + nn];
    else             v = Wc1[k * 128 + nn];
    WT[m * 16384 + nn * 128 + k] = (_Float16)v;
}

// ---------------------------------------------------------------------------
// Kernel 1: exact KNN, one 256-thread block per point.
// R5 post-mortem: dur unchanged at ~147us despite 4x less issue work ->
// bound by the per-round serial chain (LDS broadcast + 12 ds_bpermute u64
// shuffle + block barrier) x 17 rounds. This version: each WAVE extracts its
// own top-17 independently (no barriers in the loop), with the u64 reduce in
// pure-VALU DPP; then one barrier + single-lane 4-way merge of sorted lists.
// ---------------------------------------------------------------------------
__global__ __launch_bounds__(256) void knn_kernel(
    const float* __restrict__ coords,
    const int* __restrict__ row_splits, int nseg, int n,
    int* __restrict__ nidx, float* __restrict__ ndist, int* __restrict__ idx0,
    float* __restrict__ out_nidx, float* __restrict__ out_d)
{
    const int i    = blockIdx.x;
    const int tid  = threadIdx.x;
    const int lane = tid & 63, wid = tid >> 6;

    int lo = 0, hi = n;
    for (int s = 0; s < nseg; ++s){
        int a = row_splits[s], b = row_splits[s+1];
        if (i >= a && i < b){ lo = a; hi = b; }
    }

    const float cx = coords[3*i], cy = coords[3*i+1], cz = coords[3*i+2];
    const float nrmi = __fadd_rn(__fadd_rn(__fmul_rn(cx,cx), __fmul_rn(cy,cy)), __fmul_rn(cz,cz));

    const int jbase = lo + tid;
    const float FINF = __uint_as_float(0x7f800000u);

    __shared__ float d2s[CMAX][256];      // 20 KB backup of per-lane d2
    __shared__ ull   wl[4][KNB+1];        // per-wave sorted top-17
    __shared__ ull   mg[KNB+1];           // merged top-17

    // ---- pass 1: distances + LDS backup + per-lane top-3 ----
    ull m1 = ~0ull, m2 = ~0ull, m3 = ~0ull;
    #pragma unroll
    for (int c = 0; c < CMAX; ++c){
        int j = jbase + c*256;
        float dv = FINF;
        if (j < hi){
            const float* cp = coords + 3*j;
            float x = cp[0], y = cp[1], z = cp[2];
            float nrmj = __fadd_rn(__fadd_rn(__fmul_rn(x,x), __fmul_rn(y,y)), __fmul_rn(z,z));
            float dot  = __fadd_rn(__fadd_rn(__fmul_rn(cx,x), __fmul_rn(cy,y)), __fmul_rn(cz,z));
            float d2 = __fsub_rn(__fadd_rn(nrmi, nrmj), __fmul_rn(2.0f, dot));
            dv = fmaxf(d2, 0.0f);
        }
        d2s[c][tid] = dv;
        ull kk = (((ull)__float_as_uint(dv)) << 32) | (unsigned int)(j);
        ull n1 = kk < m1 ? kk : m1;
        ull t1 = kk < m1 ? m1 : kk;
        ull n2 = t1 < m2 ? t1 : m2;
        ull t2 = t1 < m2 ? m2 : t1;
        ull n3 = t2 < m3 ? t2 : m3;
        m1 = n1; m2 = n2; m3 = n3;
    }
    int vcnt = 3;

    // ---- per-wave top-17 extraction (no barriers, DPP reduce) ----
    ull keep = ~0ull;
    for (int r = 0; r < KNB + 1; ++r){
        ull b = wave_min_u64(m1);
        if (lane == r) keep = b;
        if (m1 == b){
            m1 = m2; m2 = m3; m3 = ~0ull;
            if (--vcnt == 0){
                // rare refill: 3 smallest local keys strictly greater than b
                m1 = m2 = m3 = ~0ull;
                #pragma unroll
                for (int c = 0; c < CMAX; ++c){
                    float dv2 = d2s[c][tid];
                    ull kk = (((ull)__float_as_uint(dv2)) << 32) | (unsigned int)(jbase + c*256);
                    kk = kk > b ? kk : ~0ull;
                    ull n1 = kk < m1 ? kk : m1;
                    ull t1 = kk < m1 ? m1 : kk;
                    ull n2 = t1 < m2 ? t1 : m2;
                    ull t2 = t1 < m2 ? m2 : t1;
                    ull n3 = t2 < m3 ? t2 : m3;
                    m1 = n1; m2 = n2; m3 = n3;
                }
                vcnt = 3;
            }
        }
    }
    if (lane < KNB + 1) wl[wid][lane] = keep;
    __syncthreads();

    // ---- single-lane 4-way merge of the sorted lists ----
    if (tid == 0){
        int p0 = 0, p1 = 0, p2 = 0, p3 = 0;
        for (int r = 0; r < KNB + 1; ++r){
            ull v0 = (p0 <= KNB) ? wl[0][p0] : ~0ull;
            ull v1 = (p1 <= KNB) ? wl[1][p1] : ~0ull;
            ull v2 = (p2 <= KNB) ? wl[2][p2] : ~0ull;
            ull v3 = (p3 <= KNB) ? wl[3][p3] : ~0ull;
            ull b = v0; int bi = 0;
            if (v1 < b){ b = v1; bi = 1; }
            if (v2 < b){ b = v2; bi = 2; }
            if (v3 < b){ b = v3; bi = 3; }
            if (bi == 0) ++p0; else if (bi == 1) ++p1; else if (bi == 2) ++p2; else ++p3;
            mg[r] = b;
        }
    }
    __syncthreads();

    if (tid == 0) idx0[i] = (int)(mg[0] & 0xffffffffull);
    if (tid >= 1 && tid <= KNB){
        ull b = mg[tid];
        int   j  = (int)(b & 0xffffffffull);
        float dv = __uint_as_float((unsigned int)(b >> 32));
        int rr = tid - 1;
        nidx[i*KNB + rr]     = j;
        ndist[i*KNB + rr]    = dv;
        out_nidx[i*KNB + rr] = (float)j;
        out_d[i*KNB + rr]    = dv;
    }
}

// ---------------------------------------------------------------------------
// Kernel 2: 4 nodes (64 edges) per 256-thread block. Edge MLP only now:
// e1/e2/c1 MFMA + c2 + e_sum + coords update; writes agg=[e_sum|h_self] to
// global for the batched node-MLP kernel (R5: node MLP per-block was ~half
// the VALU at 2.5 blocks/CU residency).
// ---------------------------------------------------------------------------
__global__ __launch_bounds__(256, 3) void egcn_node_kernel(
    const float* __restrict__ h, const float* __restrict__ coords,
    const int* __restrict__ nidx, const float* __restrict__ ndist,
    const int* __restrict__ idx0, const _Float16* __restrict__ WTg,
    const float* __restrict__ W_e1, const float* __restrict__ b_e1,
    const float* __restrict__ b_e2, const float* __restrict__ b_c1,
    const float* __restrict__ W_c2, const float* __restrict__ b_c2,
    float* __restrict__ aggout, float* __restrict__ out_coords, int n)
{
    __shared__ _Float16 Act[64 * SA];                       // 16640 B
    __shared__ unsigned int wt[128 * SW];                   // 33280 B
    __shared__ float agg[4][HDIM];
    __shared__ float dls[64];
    __shared__ int   nb[64];
    __shared__ int   j0s[4];
    __shared__ float wedge[64];
    __shared__ float wedgep[2][64];

    const int g0  = blockIdx.x * 4;
    const int tid = threadIdx.x;
    const int lane = tid & 63, wid = tid >> 6;
    const int ln31 = lane & 31, grp = lane >> 5;
    const int rt  = wid & 1;
    const int ct0 = (wid >> 1) * 2;

    if (tid < 64){
        int e = min(g0*KNB + tid, n*KNB - 1);
        nb[tid]  = nidx[e];
        dls[tid] = ndist[e];
    }
    if (tid < 4) j0s[tid] = idx0[min(g0 + tid, n - 1)];
    __syncthreads();

    unsigned int* actd = (unsigned int*)Act;

    {
        int r = tid >> 2, q = tid & 3, f0 = q * 16;
        const float* hs = h + (size_t)j0s[r >> 4] * FDIM + f0;
        const float* hn = h + (size_t)nb[r] * FDIM + f0;
        unsigned int ds = (unsigned int)(r * SA + f0) >> 1;
        unsigned int dn = (unsigned int)(r * SA + FDIM + f0) >> 1;
        #pragma unroll
        for (int j = 0; j < 8; ++j){
            actd[ds + j] = pack2(hs[2*j], hs[2*j+1]);
            actd[dn + j] = pack2(hn[2*j], hn[2*j+1]);
        }
    }
    {
        int nr = tid >> 1, kh = (tid & 1) * 64;
        const uint4* src = (const uint4*)(WTg + nr * 128 + kh);
        unsigned int* dst = wt + nr * SW + (tid & 1) * 32;
        #pragma unroll
        for (int j = 0; j < 8; ++j){
            uint4 x = src[j];
            dst[j*4+0]=x.x; dst[j*4+1]=x.y; dst[j*4+2]=x.z; dst[j*4+3]=x.w;
        }
    }
    __syncthreads();

    const unsigned int aBase  = (unsigned int)(rt*32 + ln31) * SW + grp*4;
    const unsigned int bBase0 = (unsigned int)(ct0*32 + ln31) * SW + grp*4;
    const unsigned int bBase1 = (unsigned int)((ct0+1)*32 + ln31) * SW + grp*4;

    auto gemm2 = [&](f32x16& A0, f32x16& A1){
        #pragma unroll
        for (int ks = 0; ks < 8; ++ks){
            const unsigned int off = ks * 8;
            f16x8 af  = ldfrag(actd, aBase + off);
            f16x8 bf0 = ldfrag(wt, bBase0 + off);
            f16x8 bf1 = ldfrag(wt, bBase1 + off);
            A0 = __builtin_amdgcn_mfma_f32_32x32x16_f16(af, bf0, A0, 0, 0, 0);
            A1 = __builtin_amdgcn_mfma_f32_32x32x16_f16(af, bf1, A1, 0, 0, 0);
        }
    };
    auto stage_wt = [&](const _Float16* Wg){
        int nr = tid >> 1, kh = (tid & 1) * 64;
        const uint4* src = (const uint4*)(Wg + nr * 128 + kh);
        unsigned int* dst = wt + nr * SW + (tid & 1) * 32;
        #pragma unroll
        for (int j = 0; j < 8; ++j){
            uint4 x = src[j];
            dst[j*4+0]=x.x; dst[j*4+1]=x.y; dst[j*4+2]=x.z; dst[j*4+3]=x.w;
        }
    };

    // ================= layer e1 (129 -> 128) =================
    {
        float w0a = W_e1[ct0*32 + ln31], w0b = W_e1[(ct0+1)*32 + ln31];
        float bza = b_e1[ct0*32 + ln31], bzb = b_e1[(ct0+1)*32 + ln31];
        f32x16 a0, a1;
        #pragma unroll
        for (int reg = 0; reg < 16; ++reg){
            int row32 = (reg&3) + 8*(reg>>2) + 4*grp;
            float dv = dls[rt*32 + row32];
            a0[reg] = fmaf(dv, w0a, bza);
            a1[reg] = fmaf(dv, w0b, bzb);
        }
        gemm2(a0, a1);
        __syncthreads();
        #pragma unroll
        for (int reg = 0; reg < 16; ++reg){
            int row = rt*32 + (reg&3) + 8*(reg>>2) + 4*grp;
            Act[row*SA + ct0*32 + ln31]     = (_Float16)selu_f(a0[reg]);
            Act[row*SA + (ct0+1)*32 + ln31] = (_Float16)selu_f(a1[reg]);
        }
        stage_wt(WTg + 16384);
        __syncthreads();
    }

    // ================= layer e2 (128 -> 128), e_sum fused =================
    {
        float bza = b_e2[ct0*32 + ln31], bzb = b_e2[(ct0+1)*32 + ln31];
        f32x16 a0, a1;
        #pragma unroll
        for (int reg = 0; reg < 16; ++reg){ a0[reg] = bza; a1[reg] = bzb; }
        gemm2(a0, a1);
        __syncthreads();
        float ev0[16], ev1[16];
        float slo0 = 0.f, shi0 = 0.f, slo1 = 0.f, shi1 = 0.f;
        #pragma unroll
        for (int reg = 0; reg < 16; ++reg){
            ev0[reg] = selu_f(a0[reg]);
            ev1[reg] = selu_f(a1[reg]);
            if (reg < 8){ slo0 += ev0[reg]; slo1 += ev1[reg]; }
            else        { shi0 += ev0[reg]; shi1 += ev1[reg]; }
        }
        slo0 += __shfl_xor(slo0, 32, 64);
        shi0 += __shfl_xor(shi0, 32, 64);
        slo1 += __shfl_xor(slo1, 32, 64);
        shi1 += __shfl_xor(shi1, 32, 64);
        if (grp == 0){
            agg[rt*2+0][ct0*32 + ln31]     = slo0;
            agg[rt*2+1][ct0*32 + ln31]     = shi0;
            agg[rt*2+0][(ct0+1)*32 + ln31] = slo1;
            agg[rt*2+1][(ct0+1)*32 + ln31] = shi1;
        }
        #pragma unroll
        for (int reg = 0; reg < 16; ++reg){
            int row = rt*32 + (reg&3) + 8*(reg>>2) + 4*grp;
            Act[row*SA + ct0*32 + ln31]     = (_Float16)ev0[reg];
            Act[row*SA + (ct0+1)*32 + ln31] = (_Float16)ev1[reg];
        }
        stage_wt(WTg + 2*16384);
        __syncthreads();
    }

    // ================= layer c1 (128 -> 128) + c2 fused =================
    {
        float bza = b_c1[ct0*32 + ln31], bzb = b_c1[(ct0+1)*32 + ln31];
        f32x16 a0, a1;
        #pragma unroll
        for (int reg = 0; reg < 16; ++reg){ a0[reg] = bza; a1[reg] = bzb; }
        gemm2(a0, a1);
        __syncthreads();
        float wca = W_c2[ct0*32 + ln31], wcb = W_c2[(ct0+1)*32 + ln31];
        float p[16];
        #pragma unroll
        for (int reg = 0; reg < 16; ++reg)
            p[reg] = selu_f(a0[reg]) * wca + selu_f(a1[reg]) * wcb;
        #pragma unroll
        for (int msk = 16; msk > 0; msk >>= 1){
            #pragma unroll
            for (int reg = 0; reg < 16; ++reg)
                p[reg] += __shfl_xor(p[reg], msk, 64);
        }
        if (ln31 == 0){
            #pragma unroll
            for (int reg = 0; reg < 16; ++reg){
                int row = rt*32 + (reg&3) + 8*(reg>>2) + 4*grp;
                wedgep[wid>>1][row] = p[reg];
            }
        }
        __syncthreads();
    }

    // ================= epilogue: wedge, coords, agg writeback =================
    if (tid < 64) wedge[tid] = b_c2[0] + wedgep[0][tid] + wedgep[1][tid];
    __syncthreads();

    if (tid < 12){
        int nd = tid / 3, c = tid - nd*3;
        int gi = min(g0 + nd, n - 1);
        float ci = coords[3*gi + c];
        float s = 0.f;
        #pragma unroll
        for (int k = 0; k < KNB; ++k){
            int e = nd*KNB + k;
            s += (ci - coords[3*nb[e] + c]) * wedge[e];
        }
        if (g0 + nd < n) out_coords[3*gi + c] = ci + s * (1.0f/KNB);
    }

    for (int s = tid; s < 4*192; s += 256){
        int nd = s / 192, c = s - nd*192;
        if (g0 + nd < n){
            float v = (c < HDIM) ? agg[nd][c]
                                 : h[(size_t)j0s[nd]*FDIM + (c - HDIM)];
            aggout[(size_t)(g0 + nd)*192 + c] = v;
        }
    }
}

// ---------------------------------------------------------------------------
// Kernel 3: batched node MLP, fp32. 16 nodes per 256-thread block.
// agg(192) -> selu(W_n1) -> W_n2 -> out. Activations in transposed LDS
// (row stride 20 dwords: broadcast b128 reads, 2-way write conflicts only).
// ---------------------------------------------------------------------------
#define NMB 16
__global__ __launch_bounds__(256) void node_mlp_kernel(
    const float* __restrict__ aggin,
    const float* __restrict__ W_n1, const float* __restrict__ b_n1,
    const float* __restrict__ W_n2, const float* __restrict__ b_n2,
    float* __restrict__ out, int n)
{
    __shared__ __attribute__((aligned(16))) float sinT[192][20];  // [in][nd], 15.4KB
    __shared__ float part[2][NMB][HDIM];                          // 16KB

    const int g0  = blockIdx.x * NMB;
    const int tid = threadIdx.x;
    const int o    = tid & 127;
    const int half = tid >> 7;

    // stage agg transposed: coalesced global read, scattered LDS write
    for (int s = tid; s < NMB*192; s += 256){
        size_t gidx = (size_t)g0*192 + s;
        size_t lim  = (size_t)n*192 - 1;
        float v = aggin[gidx < lim ? gidx : lim];
        int nd = s / 192, in = s - nd*192;
        sinT[in][nd] = v;
    }
    __syncthreads();

    // layer 1: 192 -> 128, K split across half
    {
        float a[NMB];
        #pragma unroll
        for (int d = 0; d < NMB; ++d) a[d] = 0.f;
        int in0 = half * 96;
        for (int in = in0; in < in0 + 96; ++in){
            float w = W_n1[in*HDIM + o];
            const float4* sp = (const float4*)&sinT[in][0];
            float4 v0 = sp[0], v1 = sp[1], v2 = sp[2], v3 = sp[3];
            a[0]  = fmaf(v0.x, w, a[0]);  a[1]  = fmaf(v0.y, w, a[1]);
            a[2]  = fmaf(v0.z, w, a[2]);  a[3]  = fmaf(v0.w, w, a[3]);
            a[4]  = fmaf(v1.x, w, a[4]);  a[5]  = fmaf(v1.y, w, a[5]);
            a[6]  = fmaf(v1.z, w, a[6]);  a[7]  = fmaf(v1.w, w, a[7]);
            a[8]  = fmaf(v2.x, w, a[8]);  a[9]  = fmaf(v2.y, w, a[9]);
            a[10] = fmaf(v2.z, w, a[10]); a[11] = fmaf(v2.w, w, a[11]);
            a[12] = fmaf(v3.x, w, a[12]); a[13] = fmaf(v3.y, w, a[13]);
            a[14] = fmaf(v3.z, w, a[14]); a[15] = fmaf(v3.w, w, a[15]);
        }
        #pragma unroll
        for (int d = 0; d < NMB; ++d) part[half][d][o] = a[d];
    }
    __syncthreads();

    // combine + selu -> back into sinT (first 128 rows)
    for (int s = tid; s < NMB*HDIM; s += 256){
        int nd = s >> 7, o2 = s & 127;
        sinT[o2][nd] = selu_f(part[0][nd][o2] + part[1][nd][o2] + b_n1[o2]);
    }
    __syncthreads();

    // layer 2: 128 -> 128, K split across half
    {
        float a[NMB];
        #pragma unroll
        for (int d = 0; d < NMB; ++d) a[d] = 0.f;
        int in0 = half * 64;
        for (int in = in0; in < in0 + 64; ++in){
            float w = W_n2[in*HDIM + o];
            const float4* sp = (const float4*)&sinT[in][0];
            float4 v0 = sp[0], v1 = sp[1], v2 = sp[2], v3 = sp[3];
            a[0]  = fmaf(v0.x, w, a[0]);  a[1]  = fmaf(v0.y, w, a[1]);
            a[2]  = fmaf(v0.z, w, a[2]);  a[3]  = fmaf(v0.w, w, a[3]);
            a[4]  = fmaf(v1.x, w, a[4]);  a[5]  = fmaf(v1.y, w, a[5]);
            a[6]  = fmaf(v1.z, w, a[6]);  a[7]  = fmaf(v1.w, w, a[7]);
            a[8]  = fmaf(v2.x, w, a[8]);  a[9]  = fmaf(v2.y, w, a[9]);
            a[10] = fmaf(v2.z, w, a[10]); a[11] = fmaf(v2.w, w, a[11]);
            a[12] = fmaf(v3.x, w, a[12]); a[13] = fmaf(v3.y, w, a[13]);
            a[14] = fmaf(v3.z, w, a[14]); a[15] = fmaf(v3.w, w, a[15]);
        }
        #pragma unroll
        for (int d = 0; d < NMB; ++d) part[half][d][o] = a[d];
    }
    __syncthreads();

    for (int s = tid; s < NMB*HDIM; s += 256){
        int nd = s >> 7, o2 = s & 127;
        if (g0 + nd < n)
            out[(size_t)(g0 + nd)*HDIM + o2] =
                part[0][nd][o2] + part[1][nd][o2] + b_n2[o2];
    }
}

extern "C" void kernel_launch(void* const* d_in, const int* in_sizes, int n_in,
                              void* d_out, int out_size, void* d_ws, size_t ws_size,
                              hipStream_t stream)
{
    const float* h          = (const float*)d_in[0];
    const float* coords     = (const float*)d_in[1];
    const int*   row_splits = (const int*)  d_in[2];
    const float* W_e1 = (const float*)d_in[3];
    const float* b_e1 = (const float*)d_in[4];
    const float* W_e2 = (const float*)d_in[5];
    const float* b_e2 = (const float*)d_in[6];
    const float* W_c1 = (const float*)d_in[7];
    const float* b_c1 = (const float*)d_in[8];
    const float* W_c2 = (const float*)d_in[9];
    const float* b_c2 = (const float*)d_in[10];
    const float* W_n1 = (const float*)d_in[11];
    const float* b_n1 = (const float*)d_in[12];
    const float* W_n2 = (const float*)d_in[13];
    const float* b_n2 = (const float*)d_in[14];

    const int n    = in_sizes[0] / FDIM;
    const int nseg = in_sizes[2] - 1;

    float* out        = (float*)d_out;
    float* out_coords = out + (size_t)n * HDIM;
    float* out_nidx   = out_coords + (size_t)n * 3;
    float* out_d      = out_nidx + (size_t)n * KNB;

    int*       nidx_i = (int*)d_ws;
    float*     ndist  = (float*)(nidx_i + (size_t)n * KNB);
    int*       idx0   = (int*)(ndist + (size_t)n * KNB);
    _Float16*  WT     = (_Float16*)(idx0 + (size_t)n);       // 3 x 128 x 128 fp16
    float*     aggbuf = (float*)(WT + 3 * 16384);            // n x 192 fp32

    conv_kernel<<<192, 256, 0, stream>>>(W_e1, W_e2, W_c1, WT);

    knn_kernel<<<n, 256, 0, stream>>>(coords, row_splits, nseg, n,
                                      nidx_i, ndist, idx0, out_nidx, out_d);

    egcn_node_kernel<<<(n + 3) / 4, 256, 0, stream>>>(
        h, coords, nidx_i, ndist, idx0, WT,
        W_e1, b_e1, b_e2, b_c1, W_c2, b_c2,
        aggbuf, out_coords, n);

    node_mlp_kernel<<<(n + NMB - 1) / NMB, 256, 0, stream>>>(
        aggbuf, W_n1, b_n1, W_n2, b_n2, out, n);
}

// Round 7
// 285.679 us; speedup vs baseline: 1.0768x; 1.0768x over previous
//
#include <hip/hip_runtime.h>
#include <cstdint>

#define KNB 16
#define FDIM 64
#define HDIM 128
#define SA 130          // Act row stride in f16 units (65 dwords -> conflict-free)
#define SW 65           // WT row stride in dwords
#define CMAXW 80        // candidates per lane, wave-per-point (up to 5120/segment)

typedef unsigned long long ull;
typedef _Float16 f16x8 __attribute__((ext_vector_type(8)));
typedef float    f32x16 __attribute__((ext_vector_type(16)));

__device__ __forceinline__ float selu_f(float x){
    const float a = 1.6732632423543772f, s = 1.0507009873554805f;
    return x > 0.f ? s * x : s * a * expm1f(x);
}

__device__ __forceinline__ unsigned int pack2(float a, float b){
    union { _Float16 h[2]; unsigned int u; } t;
    t.h[0] = (_Float16)a; t.h[1] = (_Float16)b;
    return t.u;
}

__device__ __forceinline__ f16x8 ldfrag(const unsigned int* p, unsigned int di){
    union { unsigned int u[4]; f16x8 v; } t;
    t.u[0] = p[di]; t.u[1] = p[di+1]; t.u[2] = p[di+2]; t.u[3] = p[di+3];
    return t.v;
}

// ---- u32 min-reduce across a wave64 in pure-VALU DPP ----
template<int CTRL>
__device__ __forceinline__ unsigned int dppmin_u32(unsigned int v){
    unsigned int t = (unsigned int)__builtin_amdgcn_update_dpp(
        -1, (int)v, CTRL, 0xF, 0xF, false);
    return t < v ? t : v;
}
__device__ __forceinline__ unsigned int wave_min_u32(unsigned int v){
    v = dppmin_u32<0x111>(v);   // row_shr:1
    v = dppmin_u32<0x112>(v);   // row_shr:2
    v = dppmin_u32<0x114>(v);   // row_shr:4
    v = dppmin_u32<0x118>(v);   // row_shr:8
    v = dppmin_u32<0x142>(v);   // row_bcast:15
    v = dppmin_u32<0x143>(v);   // row_bcast:31
    return (unsigned int)__builtin_amdgcn_readlane((int)v, 63);
}

// ---------------------------------------------------------------------------
// Kernel 0: weights -> transposed fp16 (WT[n][k] = W[k][n]).
// ---------------------------------------------------------------------------
__global__ __launch_bounds__(256) void conv_kernel(
    const float* __restrict__ We1, const float* __restrict__ We2,
    const float* __restrict__ Wc1, _Float16* __restrict__ WT)
{
    int id = blockIdx.x * 256 + threadIdx.x;     // 0..49151
    int m  = id >> 14;
    int r  = id & 16383;
    int nn = (r >> 7) & 127;
    int k  = r & 127;
    float v;
    if (m == 0)      v = We1[(k + 1) * 128 + nn];
    else if (m == 1) v = We2[k * 128 + nn];
    else             v = Wc1[k * 128 + nn];
    WT[m * 16384 + nn * 128 + k] = (_Float16)v;
}

// ---------------------------------------------------------------------------
// Kernel 1: exact KNN, ONE WAVE PER POINT (4 points / 256-block, no LDS,
// no barriers). R6 post-mortem: VALUBusy ~100% at 4100 inst/wave -- the
// per-lane refill was if-converted and issued every round (17 x ~260 inst).
// Fixes: (a) wave-uniform scalar branch around refill (s_cbranch, never
// issues when not taken); (b) refill recomputes d2 from coords (L2-hot,
// P~1e-2/point) -- LDS backup deleted; (c) two-stage u32 DPP min replaces
// u64 reduce (exact (d2,j) order); (d) owner lane writes outputs in-round,
// merge stage deleted. ~2900 inst/wave vs R6's 4100 x 4 waves.
// ---------------------------------------------------------------------------
__global__ __launch_bounds__(256) void knn_kernel(
    const float* __restrict__ coords,
    const int* __restrict__ row_splits, int nseg, int n,
    int* __restrict__ nidx, float* __restrict__ ndist, int* __restrict__ idx0,
    float* __restrict__ out_nidx, float* __restrict__ out_d)
{
    const int lane = threadIdx.x & 63;
    const int wid  = threadIdx.x >> 6;
    const int i    = blockIdx.x * 4 + wid;
    if (i >= n) return;

    int lo = 0, hi = n;
    for (int s = 0; s < nseg; ++s){
        int a = row_splits[s], b = row_splits[s+1];
        if (i >= a && i < b){ lo = a; hi = b; }
    }

    const float cx = coords[3*i], cy = coords[3*i+1], cz = coords[3*i+2];
    const float nrmi = __fadd_rn(__fadd_rn(__fmul_rn(cx,cx), __fmul_rn(cy,cy)), __fmul_rn(cz,cz));

    const int jbase = lo + lane;
    const float FINF = __uint_as_float(0x7f800000u);

    // ---- pass 1: distances + per-lane sorted top-3 (u64 keys, named regs) ----
    ull m1 = ~0ull, m2 = ~0ull, m3 = ~0ull;
    {
        const float* cp = coords + (size_t)3 * jbase;
        for (int c = 0; c < CMAXW; ++c){
            int j = jbase + c*64;
            float dv = FINF;
            if (j < hi){
                float x = cp[0], y = cp[1], z = cp[2];
                float nrmj = __fadd_rn(__fadd_rn(__fmul_rn(x,x), __fmul_rn(y,y)), __fmul_rn(z,z));
                float dot  = __fadd_rn(__fadd_rn(__fmul_rn(cx,x), __fmul_rn(cy,y)), __fmul_rn(cz,z));
                float d2 = __fsub_rn(__fadd_rn(nrmi, nrmj), __fmul_rn(2.0f, dot));
                dv = fmaxf(d2, 0.0f);
            }
            cp += 192;   // 64 points * 3 floats
            ull kk = (((ull)__float_as_uint(dv)) << 32) | (unsigned int)j;
            ull n1 = kk < m1 ? kk : m1;
            ull t1 = kk < m1 ? m1 : kk;
            ull n2 = t1 < m2 ? t1 : m2;
            ull t2 = t1 < m2 ? m2 : t1;
            ull n3 = t2 < m3 ? t2 : m3;
            m1 = n1; m2 = n2; m3 = n3;
        }
    }
    int vcnt = 3;

    // ---- 17 extraction rounds, all in-wave ----
    for (int r = 0; r < KNB + 1; ++r){
        unsigned int h32 = (unsigned int)(m1 >> 32);
        unsigned int l32 = (unsigned int)m1;
        unsigned int wmd = wave_min_u32(h32);
        unsigned int jm  = (h32 == wmd) ? l32 : 0xFFFFFFFFu;
        unsigned int wmj = wave_min_u32(jm);

        bool own = (h32 == wmd) && (l32 == wmj);
        bool need = false;
        if (own){
            int   j  = (int)wmj;
            float dv = __uint_as_float(wmd);
            if (r == 0){
                idx0[i] = j;
            } else {
                int rr = r - 1;
                nidx[i*KNB + rr]     = j;
                ndist[i*KNB + rr]    = dv;
                out_nidx[i*KNB + rr] = (float)j;
                out_d[i*KNB + rr]    = dv;
            }
            m1 = m2; m2 = m3; m3 = ~0ull;
            need = (--vcnt == 0);
        }

        // rare refill: wave-uniform scalar branch so the body never issues
        // unless some lane exhausted its top-3 cache
        if (__ballot((int)need)){
            if (need){
                ull b = (((ull)wmd) << 32) | wmj;
                m1 = m2 = m3 = ~0ull;
                const float* cq = coords + (size_t)3 * jbase;
                for (int c = 0; c < CMAXW; ++c){
                    int j = jbase + c*64;
                    float dv = FINF;
                    if (j < hi){
                        float x = cq[0], y = cq[1], z = cq[2];
                        float nrmj = __fadd_rn(__fadd_rn(__fmul_rn(x,x), __fmul_rn(y,y)), __fmul_rn(z,z));
                        float dot  = __fadd_rn(__fadd_rn(__fmul_rn(cx,x), __fmul_rn(cy,y)), __fmul_rn(cz,z));
                        float d2 = __fsub_rn(__fadd_rn(nrmi, nrmj), __fmul_rn(2.0f, dot));
                        dv = fmaxf(d2, 0.0f);
                    }
                    cq += 192;
                    ull kk = (((ull)__float_as_uint(dv)) << 32) | (unsigned int)j;
                    kk = kk > b ? kk : ~0ull;   // keys <= b are provably extracted
                    ull n1 = kk < m1 ? kk : m1;
                    ull t1 = kk < m1 ? m1 : kk;
                    ull n2 = t1 < m2 ? t1 : m2;
                    ull t2 = t1 < m2 ? m2 : t1;
                    ull n3 = t2 < m3 ? t2 : m3;
                    m1 = n1; m2 = n2; m3 = n3;
                }
                vcnt = 3;
            }
        }
    }
}

// ---------------------------------------------------------------------------
// Kernel 2: 4 nodes (64 edges) per 256-thread block. Edge MLP (e1/e2/c1)
// as f16 MFMA + c2 + e_sum + coords update; writes agg=[e_sum|h_self].
// (unchanged this round)
// ---------------------------------------------------------------------------
__global__ __launch_bounds__(256, 3) void egcn_node_kernel(
    const float* __restrict__ h, const float* __restrict__ coords,
    const int* __restrict__ nidx, const float* __restrict__ ndist,
    const int* __restrict__ idx0, const _Float16* __restrict__ WTg,
    const float* __restrict__ W_e1, const float* __restrict__ b_e1,
    const float* __restrict__ b_e2, const float* __restrict__ b_c1,
    const float* __restrict__ W_c2, const float* __restrict__ b_c2,
    float* __restrict__ aggout, float* __restrict__ out_coords, int n)
{
    __shared__ _Float16 Act[64 * SA];                       // 16640 B
    __shared__ unsigned int wt[128 * SW];                   // 33280 B
    __shared__ float agg[4][HDIM];
    __shared__ float dls[64];
    __shared__ int   nb[64];
    __shared__ int   j0s[4];
    __shared__ float wedge[64];
    __shared__ float wedgep[2][64];

    const int g0  = blockIdx.x * 4;
    const int tid = threadIdx.x;
    const int lane = tid & 63, wid = tid >> 6;
    const int ln31 = lane & 31, grp = lane >> 5;
    const int rt  = wid & 1;
    const int ct0 = (wid >> 1) * 2;

    if (tid < 64){
        int e = min(g0*KNB + tid, n*KNB - 1);
        nb[tid]  = nidx[e];
        dls[tid] = ndist[e];
    }
    if (tid < 4) j0s[tid] = idx0[min(g0 + tid, n - 1)];
    __syncthreads();

    unsigned int* actd = (unsigned int*)Act;

    {
        int r = tid >> 2, q = tid & 3, f0 = q * 16;
        const float* hs = h + (size_t)j0s[r >> 4] * FDIM + f0;
        const float* hn = h + (size_t)nb[r] * FDIM + f0;
        unsigned int ds = (unsigned int)(r * SA + f0) >> 1;
        unsigned int dn = (unsigned int)(r * SA + FDIM + f0) >> 1;
        #pragma unroll
        for (int j = 0; j < 8; ++j){
            actd[ds + j] = pack2(hs[2*j], hs[2*j+1]);
            actd[dn + j] = pack2(hn[2*j], hn[2*j+1]);
        }
    }
    {
        int nr = tid >> 1, kh = (tid & 1) * 64;
        const uint4* src = (const uint4*)(WTg + nr * 128 + kh);
        unsigned int* dst = wt + nr * SW + (tid & 1) * 32;
        #pragma unroll
        for (int j = 0; j < 8; ++j){
            uint4 x = src[j];
            dst[j*4+0]=x.x; dst[j*4+1]=x.y; dst[j*4+2]=x.z; dst[j*4+3]=x.w;
        }
    }
    __syncthreads();

    const unsigned int aBase  = (unsigned int)(rt*32 + ln31) * SW + grp*4;
    const unsigned int bBase0 = (unsigned int)(ct0*32 + ln31) * SW + grp*4;
    const unsigned int bBase1 = (unsigned int)((ct0+1)*32 + ln31) * SW + grp*4;

    auto gemm2 = [&](f32x16& A0, f32x16& A1){
        #pragma unroll
        for (int ks = 0; ks < 8; ++ks){
            const unsigned int off = ks * 8;
            f16x8 af  = ldfrag(actd, aBase + off);
            f16x8 bf0 = ldfrag(wt, bBase0 + off);
            f16x8 bf1 = ldfrag(wt, bBase1 + off);
            A0 = __builtin_amdgcn_mfma_f32_32x32x16_f16(af, bf0, A0, 0, 0, 0);
            A1 = __builtin_amdgcn_mfma_f32_32x32x16_f16(af, bf1, A1, 0, 0, 0);
        }
    };
    auto stage_wt = [&](const _Float16* Wg){
        int nr = tid >> 1, kh = (tid & 1) * 64;
        const uint4* src = (const uint4*)(Wg + nr * 128 + kh);
        unsigned int* dst = wt + nr * SW + (tid & 1) * 32;
        #pragma unroll
        for (int j = 0; j < 8; ++j){
            uint4 x = src[j];
            dst[j*4+0]=x.x; dst[j*4+1]=x.y; dst[j*4+2]=x.z; dst[j*4+3]=x.w;
        }
    };

    // ================= layer e1 (129 -> 128) =================
    {
        float w0a = W_e1[ct0*32 + ln31], w0b = W_e1[(ct0+1)*32 + ln31];
        float bza = b_e1[ct0*32 + ln31], bzb = b_e1[(ct0+1)*32 + ln31];
        f32x16 a0, a1;
        #pragma unroll
        for (int reg = 0; reg < 16; ++reg){
            int row32 = (reg&3) + 8*(reg>>2) + 4*grp;
            float dv = dls[rt*32 + row32];
            a0[reg] = fmaf(dv, w0a, bza);
            a1[reg] = fmaf(dv, w0b, bzb);
        }
        gemm2(a0, a1);
        __syncthreads();
        #pragma unroll
        for (int reg = 0; reg < 16; ++reg){
            int row = rt*32 + (reg&3) + 8*(reg>>2) + 4*grp;
            Act[row*SA + ct0*32 + ln31]     = (_Float16)selu_f(a0[reg]);
            Act[row*SA + (ct0+1)*32 + ln31] = (_Float16)selu_f(a1[reg]);
        }
        stage_wt(WTg + 16384);
        __syncthreads();
    }

    // ================= layer e2 (128 -> 128), e_sum fused =================
    {
        float bza = b_e2[ct0*32 + ln31], bzb = b_e2[(ct0+1)*32 + ln31];
        f32x16 a0, a1;
        #pragma unroll
        for (int reg = 0; reg < 16; ++reg){ a0[reg] = bza; a1[reg] = bzb; }
        gemm2(a0, a1);
        __syncthreads();
        float ev0[16], ev1[16];
        float slo0 = 0.f, shi0 = 0.f, slo1 = 0.f, shi1 = 0.f;
        #pragma unroll
        for (int reg = 0; reg < 16; ++reg){
            ev0[reg] = selu_f(a0[reg]);
            ev1[reg] = selu_f(a1[reg]);
            if (reg < 8){ slo0 += ev0[reg]; slo1 += ev1[reg]; }
            else        { shi0 += ev0[reg]; shi1 += ev1[reg]; }
        }
        slo0 += __shfl_xor(slo0, 32, 64);
        shi0 += __shfl_xor(shi0, 32, 64);
        slo1 += __shfl_xor(slo1, 32, 64);
        shi1 += __shfl_xor(shi1, 32, 64);
        if (grp == 0){
            agg[rt*2+0][ct0*32 + ln31]     = slo0;
            agg[rt*2+1][ct0*32 + ln31]     = shi0;
            agg[rt*2+0][(ct0+1)*32 + ln31] = slo1;
            agg[rt*2+1][(ct0+1)*32 + ln31] = shi1;
        }
        #pragma unroll
        for (int reg = 0; reg < 16; ++reg){
            int row = rt*32 + (reg&3) + 8*(reg>>2) + 4*grp;
            Act[row*SA + ct0*32 + ln31]     = (_Float16)ev0[reg];
            Act[row*SA + (ct0+1)*32 + ln31] = (_Float16)ev1[reg];
        }
        stage_wt(WTg + 2*16384);
        __syncthreads();
    }

    // ================= layer c1 (128 -> 128) + c2 fused =================
    {
        float bza = b_c1[ct0*32 + ln31], bzb = b_c1[(ct0+1)*32 + ln31];
        f32x16 a0, a1;
        #pragma unroll
        for (int reg = 0; reg < 16; ++reg){ a0[reg] = bza; a1[reg] = bzb; }
        gemm2(a0, a1);
        __syncthreads();
        float wca = W_c2[ct0*32 + ln31], wcb = W_c2[(ct0+1)*32 + ln31];
        float p[16];
        #pragma unroll
        for (int reg = 0; reg < 16; ++reg)
            p[reg] = selu_f(a0[reg]) * wca + selu_f(a1[reg]) * wcb;
        #pragma unroll
        for (int msk = 16; msk > 0; msk >>= 1){
            #pragma unroll
            for (int reg = 0; reg < 16; ++reg)
                p[reg] += __shfl_xor(p[reg], msk, 64);
        }
        if (ln31 == 0){
            #pragma unroll
            for (int reg = 0; reg < 16; ++reg){
                int row = rt*32 + (reg&3) + 8*(reg>>2) + 4*grp;
                wedgep[wid>>1][row] = p[reg];
            }
        }
        __syncthreads();
    }

    // ================= epilogue: wedge, coords, agg writeback =================
    if (tid < 64) wedge[tid] = b_c2[0] + wedgep[0][tid] + wedgep[1][tid];
    __syncthreads();

    if (tid < 12){
        int nd = tid / 3, c = tid - nd*3;
        int gi = min(g0 + nd, n - 1);
        float ci = coords[3*gi + c];
        float s = 0.f;
        #pragma unroll
        for (int k = 0; k < KNB; ++k){
            int e = nd*KNB + k;
            s += (ci - coords[3*nb[e] + c]) * wedge[e];
        }
        if (g0 + nd < n) out_coords[3*gi + c] = ci + s * (1.0f/KNB);
    }

    for (int s = tid; s < 4*192; s += 256){
        int nd = s / 192, c = s - nd*192;
        if (g0 + nd < n){
            float v = (c < HDIM) ? agg[nd][c]
                                 : h[(size_t)j0s[nd]*FDIM + (c - HDIM)];
            aggout[(size_t)(g0 + nd)*192 + c] = v;
        }
    }
}

// ---------------------------------------------------------------------------
// Kernel 3: batched node MLP, fp32. 16 nodes per 256-thread block.
// (unchanged this round)
// ---------------------------------------------------------------------------
#define NMB 16
__global__ __launch_bounds__(256) void node_mlp_kernel(
    const float* __restrict__ aggin,
    const float* __restrict__ W_n1, const float* __restrict__ b_n1,
    const float* __restrict__ W_n2, const float* __restrict__ b_n2,
    float* __restrict__ out, int n)
{
    __shared__ __attribute__((aligned(16))) float sinT[192][20];  // [in][nd]
    __shared__ float part[2][NMB][HDIM];

    const int g0  = blockIdx.x * NMB;
    const int tid = threadIdx.x;
    const int o    = tid & 127;
    const int half = tid >> 7;

    for (int s = tid; s < NMB*192; s += 256){
        size_t gidx = (size_t)g0*192 + s;
        size_t lim  = (size_t)n*192 - 1;
        float v = aggin[gidx < lim ? gidx : lim];
        int nd = s / 192, in = s - nd*192;
        sinT[in][nd] = v;
    }
    __syncthreads();

    {
        float a[NMB];
        #pragma unroll
        for (int d = 0; d < NMB; ++d) a[d] = 0.f;
        int in0 = half * 96;
        for (int in = in0; in < in0 + 96; ++in){
            float w = W_n1[in*HDIM + o];
            const float4* sp = (const float4*)&sinT[in][0];
            float4 v0 = sp[0], v1 = sp[1], v2 = sp[2], v3 = sp[3];
            a[0]  = fmaf(v0.x, w, a[0]);  a[1]  = fmaf(v0.y, w, a[1]);
            a[2]  = fmaf(v0.z, w, a[2]);  a[3]  = fmaf(v0.w, w, a[3]);
            a[4]  = fmaf(v1.x, w, a[4]);  a[5]  = fmaf(v1.y, w, a[5]);
            a[6]  = fmaf(v1.z, w, a[6]);  a[7]  = fmaf(v1.w, w, a[7]);
            a[8]  = fmaf(v2.x, w, a[8]);  a[9]  = fmaf(v2.y, w, a[9]);
            a[10] = fmaf(v2.z, w, a[10]); a[11] = fmaf(v2.w, w, a[11]);
            a[12] = fmaf(v3.x, w, a[12]); a[13] = fmaf(v3.y, w, a[13]);
            a[14] = fmaf(v3.z, w, a[14]); a[15] = fmaf(v3.w, w, a[15]);
        }
        #pragma unroll
        for (int d = 0; d < NMB; ++d) part[half][d][o] = a[d];
    }
    __syncthreads();

    for (int s = tid; s < NMB*HDIM; s += 256){
        int nd = s >> 7, o2 = s & 127;
        sinT[o2][nd] = selu_f(part[0][nd][o2] + part[1][nd][o2] + b_n1[o2]);
    }
    __syncthreads();

    {
        float a[NMB];
        #pragma unroll
        for (int d = 0; d < NMB; ++d) a[d] = 0.f;
        int in0 = half * 64;
        for (int in = in0; in < in0 + 64; ++in){
            float w = W_n2[in*HDIM + o];
            const float4* sp = (const float4*)&sinT[in][0];
            float4 v0 = sp[0], v1 = sp[1], v2 = sp[2], v3 = sp[3];
            a[0]  = fmaf(v0.x, w, a[0]);  a[1]  = fmaf(v0.y, w, a[1]);
            a[2]  = fmaf(v0.z, w, a[2]);  a[3]  = fmaf(v0.w, w, a[3]);
            a[4]  = fmaf(v1.x, w, a[4]);  a[5]  = fmaf(v1.y, w, a[5]);
            a[6]  = fmaf(v1.z, w, a[6]);  a[7]  = fmaf(v1.w, w, a[7]);
            a[8]  = fmaf(v2.x, w, a[8]);  a[9]  = fmaf(v2.y, w, a[9]);
            a[10] = fmaf(v2.z, w, a[10]); a[11] = fmaf(v2.w, w, a[11]);
            a[12] = fmaf(v3.x, w, a[12]); a[13] = fmaf(v3.y, w, a[13]);
            a[14] = fmaf(v3.z, w, a[14]); a[15] = fmaf(v3.w, w, a[15]);
        }
        #pragma unroll
        for (int d = 0; d < NMB; ++d) part[half][d][o] = a[d];
    }
    __syncthreads();

    for (int s = tid; s < NMB*HDIM; s += 256){
        int nd = s >> 7, o2 = s & 127;
        if (g0 + nd < n)
            out[(size_t)(g0 + nd)*HDIM + o2] =
                part[0][nd][o2] + part[1][nd][o2] + b_n2[o2];
    }
}

extern "C" void kernel_launch(void* const* d_in, const int* in_sizes, int n_in,
                              void* d_out, int out_size, void* d_ws, size_t ws_size,
                              hipStream_t stream)
{
    const float* h          = (const float*)d_in[0];
    const float* coords     = (const float*)d_in[1];
    const int*   row_splits = (const int*)  d_in[2];
    const float* W_e1 = (const float*)d_in[3];
    const float* b_e1 = (const float*)d_in[4];
    const float* W_e2 = (const float*)d_in[5];
    const float* b_e2 = (const float*)d_in[6];
    const float* W_c1 = (const float*)d_in[7];
    const float* b_c1 = (const float*)d_in[8];
    const float* W_c2 = (const float*)d_in[9];
    const float* b_c2 = (const float*)d_in[10];
    const float* W_n1 = (const float*)d_in[11];
    const float* b_n1 = (const float*)d_in[12];
    const float* W_n2 = (const float*)d_in[13];
    const float* b_n2 = (const float*)d_in[14];

    const int n    = in_sizes[0] / FDIM;
    const int nseg = in_sizes[2] - 1;

    float* out        = (float*)d_out;
    float* out_coords = out + (size_t)n * HDIM;
    float* out_nidx   = out_coords + (size_t)n * 3;
    float* out_d      = out_nidx + (size_t)n * KNB;

    int*       nidx_i = (int*)d_ws;
    float*     ndist  = (float*)(nidx_i + (size_t)n * KNB);
    int*       idx0   = (int*)(ndist + (size_t)n * KNB);
    _Float16*  WT     = (_Float16*)(idx0 + (size_t)n);       // 3 x 128 x 128 fp16
    float*     aggbuf = (float*)(WT + 3 * 16384);            // n x 192 fp32

    conv_kernel<<<192, 256, 0, stream>>>(W_e1, W_e2, W_c1, WT);

    knn_kernel<<<(n + 3) / 4, 256, 0, stream>>>(coords, row_splits, nseg, n,
                                                nidx_i, ndist, idx0, out_nidx, out_d);

    egcn_node_kernel<<<(n + 3) / 4, 256, 0, stream>>>(
        h, coords, nidx_i, ndist, idx0, WT,
        W_e1, b_e1, b_e2, b_c1, W_c2, b_c2,
        aggbuf, out_coords, n);

    node_mlp_kernel<<<(n + NMB - 1) / NMB, 256, 0, stream>>>(
        aggbuf, W_n1, b_n1, W_n2, b_n2, out, n);
}

// Round 9
// 257.719 us; speedup vs baseline: 1.1937x; 1.1085x over previous
//
#include <hip/hip_runtime.h>
#include <cstdint>

#define KNB 16
#define FDIM 64
#define HDIM 128
#define NPB 8           // nodes per egcn block
#define ROWS 128        // edge rows per egcn block
#define SA 136          // Act row stride in f16 (68 dwords, 16B-aligned rows)
#define SAD 68          // Act row stride in dwords
#define SW 68           // WT row stride in dwords (16B-aligned rows)
#define CMAXW 80        // candidates per lane (segments up to 5120)

typedef unsigned long long ull;
typedef _Float16 f16x8 __attribute__((ext_vector_type(8)));
typedef float    f32x16 __attribute__((ext_vector_type(16)));

__device__ __forceinline__ float selu_f(float x){
    const float a = 1.6732632423543772f, s = 1.0507009873554805f;
    return x > 0.f ? s * x : s * a * (__expf(x) - 1.0f);
}

__device__ __forceinline__ unsigned int pack2(float a, float b){
    union { _Float16 h[2]; unsigned int u; } t;
    t.h[0] = (_Float16)a; t.h[1] = (_Float16)b;
    return t.u;
}

__device__ __forceinline__ f16x8 ldfrag4(const unsigned int* p, unsigned int di){
    union { uint4 q; f16x8 v; } t;
    t.q = *(const uint4*)(p + di);
    return t.v;
}

// ---- u32 min-reduce across a wave64 in pure-VALU DPP ----
template<int CTRL>
__device__ __forceinline__ unsigned int dppmin_u32(unsigned int v){
    unsigned int t = (unsigned int)__builtin_amdgcn_update_dpp(
        -1, (int)v, CTRL, 0xF, 0xF, false);
    return t < v ? t : v;
}
__device__ __forceinline__ unsigned int wave_min_u32(unsigned int v){
    v = dppmin_u32<0x111>(v);
    v = dppmin_u32<0x112>(v);
    v = dppmin_u32<0x114>(v);
    v = dppmin_u32<0x118>(v);
    v = dppmin_u32<0x142>(v);
    v = dppmin_u32<0x143>(v);
    return (unsigned int)__builtin_amdgcn_readlane((int)v, 63);
}

// ---------------------------------------------------------------------------
// Kernel 0a: weights -> transposed fp16 (WT[n][k] = W[k][n]).
// ---------------------------------------------------------------------------
__global__ __launch_bounds__(256) void conv_kernel(
    const float* __restrict__ We1, const float* __restrict__ We2,
    const float* __restrict__ Wc1, _Float16* __restrict__ WT)
{
    int id = blockIdx.x * 256 + threadIdx.x;
    int m  = id >> 14;
    int r  = id & 16383;
    int nn = (r >> 7) & 127;
    int k  = r & 127;
    float v;
    if (m == 0)      v = We1[(k + 1) * 128 + nn];
    else if (m == 1) v = We2[k * 128 + nn];
    else             v = Wc1[k * 128 + nn];
    WT[m * 16384 + nn * 128 + k] = (_Float16)v;
}

// ---------------------------------------------------------------------------
// Kernel 0b: coords4[j] = {x, y, z, nrm}
// ---------------------------------------------------------------------------
__global__ __launch_bounds__(256) void pack4_kernel(
    const float* __restrict__ coords, float4* __restrict__ c4, int n)
{
    int i = blockIdx.x * 256 + threadIdx.x;
    if (i < n){
        float x = coords[3*i], y = coords[3*i+1], z = coords[3*i+2];
        float nrm = __fadd_rn(__fadd_rn(__fmul_rn(x,x), __fmul_rn(y,y)), __fmul_rn(z,z));
        c4[i] = make_float4(x, y, z, nrm);
    }
}

// ---------------------------------------------------------------------------
// Kernel 1: exact KNN, one wave per point; float4 candidates, quad-unrolled.
// ---------------------------------------------------------------------------
__global__ __launch_bounds__(256) void knn_kernel(
    const float4* __restrict__ c4,
    const int* __restrict__ row_splits, int nseg, int n,
    int* __restrict__ nidx, float* __restrict__ ndist, int* __restrict__ idx0,
    float* __restrict__ out_nidx, float* __restrict__ out_d)
{
    const int lane = threadIdx.x & 63;
    const int wid  = threadIdx.x >> 6;
    const int i    = blockIdx.x * 4 + wid;
    if (i >= n) return;

    int lo = 0, hi = n;
    for (int s = 0; s < nseg; ++s){
        int a = row_splits[s], b = row_splits[s+1];
        if (i >= a && i < b){ lo = a; hi = b; }
    }

    const float4 ci = c4[i];
    const float cx = ci.x, cy = ci.y, cz = ci.z, nrmi = ci.w;

    const int jbase = lo + lane;
    const float FINF = __uint_as_float(0x7f800000u);

    ull m1 = ~0ull, m2 = ~0ull, m3 = ~0ull;

    #define D2_OF(v) __fsub_rn(__fadd_rn(nrmi, (v).w), __fmul_rn(2.0f, \
        __fadd_rn(__fadd_rn(__fmul_rn(cx,(v).x), __fmul_rn(cy,(v).y)), __fmul_rn(cz,(v).z))))
    #define INS(kk) { \
        ull n1 = (kk) < m1 ? (kk) : m1; \
        ull t1 = (kk) < m1 ? m1 : (kk); \
        ull n2 = t1 < m2 ? t1 : m2; \
        ull t2 = t1 < m2 ? m2 : t1; \
        ull n3 = t2 < m3 ? t2 : m3; \
        m1 = n1; m2 = n2; m3 = n3; }

    for (int c0 = 0; c0 < CMAXW; c0 += 4){
        int j0 = jbase + (c0+0)*64;
        int j1 = jbase + (c0+1)*64;
        int j2 = jbase + (c0+2)*64;
        int j3 = jbase + (c0+3)*64;
        float4 v0 = c4[min(j0, hi-1)];
        float4 v1 = c4[min(j1, hi-1)];
        float4 v2 = c4[min(j2, hi-1)];
        float4 v3 = c4[min(j3, hi-1)];
        float d0 = (j0 < hi) ? fmaxf(D2_OF(v0), 0.0f) : FINF;
        float d1 = (j1 < hi) ? fmaxf(D2_OF(v1), 0.0f) : FINF;
        float d2 = (j2 < hi) ? fmaxf(D2_OF(v2), 0.0f) : FINF;
        float d3 = (j3 < hi) ? fmaxf(D2_OF(v3), 0.0f) : FINF;
        ull k0 = (((ull)__float_as_uint(d0)) << 32) | (unsigned int)j0;
        ull k1 = (((ull)__float_as_uint(d1)) << 32) | (unsigned int)j1;
        ull k2 = (((ull)__float_as_uint(d2)) << 32) | (unsigned int)j2;
        ull k3 = (((ull)__float_as_uint(d3)) << 32) | (unsigned int)j3;
        INS(k0) INS(k1) INS(k2) INS(k3)
    }
    int vcnt = 3;

    for (int r = 0; r < KNB + 1; ++r){
        unsigned int h32 = (unsigned int)(m1 >> 32);
        unsigned int l32 = (unsigned int)m1;
        unsigned int wmd = wave_min_u32(h32);
        unsigned int jm  = (h32 == wmd) ? l32 : 0xFFFFFFFFu;
        unsigned int wmj = wave_min_u32(jm);

        bool own = (h32 == wmd) && (l32 == wmj);
        bool need = false;
        if (own){
            int   j  = (int)wmj;
            float dv = __uint_as_float(wmd);
            if (r == 0){
                idx0[i] = j;
            } else {
                int rr = r - 1;
                nidx[i*KNB + rr]     = j;
                ndist[i*KNB + rr]    = dv;
                out_nidx[i*KNB + rr] = (float)j;
                out_d[i*KNB + rr]    = dv;
            }
            m1 = m2; m2 = m3; m3 = ~0ull;
            need = (--vcnt == 0);
        }

        if (__ballot((int)need)){   // wave-uniform: body never issues if untaken
            if (need){
                ull b = (((ull)wmd) << 32) | wmj;
                m1 = m2 = m3 = ~0ull;
                for (int c = 0; c < CMAXW; ++c){
                    int j = jbase + c*64;
                    float4 v = c4[min(j, hi-1)];
                    float dv = (j < hi) ? fmaxf(D2_OF(v), 0.0f) : FINF;
                    ull kk = (((ull)__float_as_uint(dv)) << 32) | (unsigned int)j;
                    kk = kk > b ? kk : ~0ull;
                    INS(kk)
                }
                vcnt = 3;
            }
        }
    }
    #undef INS
    #undef D2_OF
}

// ---------------------------------------------------------------------------
// Kernel 2: 8 nodes (128 edges) per 256-thread block, stride-68 b128 LDS.
// R8 bug fixed: stage_wt dst offset is half*32 dwords (64 f16), was half*16
// (overlapping race + dwords [48,64) of every row uninitialized -> NaN).
// ---------------------------------------------------------------------------
__global__ __launch_bounds__(256, 2) void egcn_node_kernel(
    const float* __restrict__ h, const float* __restrict__ coords,
    const int* __restrict__ nidx, const float* __restrict__ ndist,
    const int* __restrict__ idx0, const _Float16* __restrict__ WTg,
    const float* __restrict__ W_e1, const float* __restrict__ b_e1,
    const float* __restrict__ b_e2, const float* __restrict__ b_c1,
    const float* __restrict__ W_c2, const float* __restrict__ b_c2,
    float* __restrict__ aggout, float* __restrict__ out_coords, int n)
{
    __shared__ __attribute__((aligned(16))) _Float16 Act[ROWS * SA];   // 34816 B
    __shared__ __attribute__((aligned(16))) unsigned int wt[ROWS * SW];// 34816 B
    __shared__ float agg[NPB][HDIM];                                   // 4096 B
    __shared__ float dls[ROWS];
    __shared__ int   nb[ROWS];
    __shared__ int   j0s[NPB];
    __shared__ float wedge[ROWS];

    const int g0  = blockIdx.x * NPB;
    const int tid = threadIdx.x;
    const int lane = tid & 63, wid = tid >> 6;
    const int ln31 = lane & 31, grp = lane >> 5;
    const int rt  = wid;                 // row tile 0..3 (32 edge rows each)

    if (tid < ROWS){
        int e = min(g0*KNB + tid, n*KNB - 1);
        nb[tid]  = nidx[e];
        dls[tid] = ndist[e];
    }
    if (tid < NPB) j0s[tid] = idx0[min(g0 + tid, n - 1)];
    __syncthreads();

    unsigned int* actd = (unsigned int*)Act;

    // ---- stage Act = [h_self | h_neig] fp16, float4 loads + b128 stores ----
    {
        int r = tid >> 1, half = tid & 1;
        const float4* hs = (const float4*)(h + (size_t)j0s[r >> 4] * FDIM + half*32);
        const float4* hn = (const float4*)(h + (size_t)nb[r] * FDIM + half*32);
        unsigned int base = (unsigned int)r * SAD + half*16;
        uint4 buf[4];
        #pragma unroll
        for (int q = 0; q < 4; ++q){
            float4 a = hs[2*q], b = hs[2*q+1];
            buf[q].x = pack2(a.x,a.y); buf[q].y = pack2(a.z,a.w);
            buf[q].z = pack2(b.x,b.y); buf[q].w = pack2(b.z,b.w);
        }
        #pragma unroll
        for (int q = 0; q < 4; ++q) *(uint4*)(actd + base + 4*q) = buf[q];
        #pragma unroll
        for (int q = 0; q < 4; ++q){
            float4 a = hn[2*q], b = hn[2*q+1];
            buf[q].x = pack2(a.x,a.y); buf[q].y = pack2(a.z,a.w);
            buf[q].z = pack2(b.x,b.y); buf[q].w = pack2(b.z,b.w);
        }
        #pragma unroll
        for (int q = 0; q < 4; ++q) *(uint4*)(actd + base + 32 + 4*q) = buf[q];
    }
    auto stage_wt = [&](const _Float16* Wg){
        int nr = tid >> 1, half = tid & 1;
        const uint4* src = (const uint4*)(Wg + nr * 128 + half*64);
        uint4* dst = (uint4*)(wt + nr * SW + half*32);   // 64 f16 = 32 dwords
        #pragma unroll
        for (int q = 0; q < 8; ++q) dst[q] = src[q];
    };
    stage_wt(WTg);
    __syncthreads();

    const unsigned int aBase = (unsigned int)(rt*32 + ln31) * SAD + grp*4;
    const unsigned int bB0   = (unsigned int)(ln31      ) * SW + grp*4;
    const unsigned int bB1   = (unsigned int)(32  + ln31) * SW + grp*4;
    const unsigned int bB2   = (unsigned int)(64  + ln31) * SW + grp*4;
    const unsigned int bB3   = (unsigned int)(96  + ln31) * SW + grp*4;

    auto gemm4 = [&](f32x16& A0, f32x16& A1, f32x16& A2, f32x16& A3){
        #pragma unroll
        for (int ks = 0; ks < 8; ++ks){
            const unsigned int off = ks * 8;
            f16x8 af = ldfrag4(actd, aBase + off);
            A0 = __builtin_amdgcn_mfma_f32_32x32x16_f16(af, ldfrag4(wt, bB0 + off), A0, 0, 0, 0);
            A1 = __builtin_amdgcn_mfma_f32_32x32x16_f16(af, ldfrag4(wt, bB1 + off), A1, 0, 0, 0);
            A2 = __builtin_amdgcn_mfma_f32_32x32x16_f16(af, ldfrag4(wt, bB2 + off), A2, 0, 0, 0);
            A3 = __builtin_amdgcn_mfma_f32_32x32x16_f16(af, ldfrag4(wt, bB3 + off), A3, 0, 0, 0);
        }
    };
    #define ROW_OF(reg) (rt*32 + ((reg)&3) + 8*((reg)>>2) + 4*grp)

    // ================= layer e1 (129 -> 128) =================
    {
        float w00 = W_e1[ln31],      w01 = W_e1[32+ln31];
        float w02 = W_e1[64+ln31],   w03 = W_e1[96+ln31];
        float bz0 = b_e1[ln31],      bz1 = b_e1[32+ln31];
        float bz2 = b_e1[64+ln31],   bz3 = b_e1[96+ln31];
        f32x16 a0, a1, a2, a3;
        #pragma unroll
        for (int reg = 0; reg < 16; ++reg){
            float dv = dls[ROW_OF(reg)];
            a0[reg] = fmaf(dv, w00, bz0);
            a1[reg] = fmaf(dv, w01, bz1);
            a2[reg] = fmaf(dv, w02, bz2);
            a3[reg] = fmaf(dv, w03, bz3);
        }
        gemm4(a0, a1, a2, a3);
        __syncthreads();
        #pragma unroll
        for (int reg = 0; reg < 16; ++reg){
            int row = ROW_OF(reg);
            Act[row*SA + ln31]      = (_Float16)selu_f(a0[reg]);
            Act[row*SA + 32 + ln31] = (_Float16)selu_f(a1[reg]);
            Act[row*SA + 64 + ln31] = (_Float16)selu_f(a2[reg]);
            Act[row*SA + 96 + ln31] = (_Float16)selu_f(a3[reg]);
        }
        stage_wt(WTg + 16384);
        __syncthreads();
    }

    // ================= layer e2 (128 -> 128), e_sum fused =================
    {
        float bz0 = b_e2[ln31],    bz1 = b_e2[32+ln31];
        float bz2 = b_e2[64+ln31], bz3 = b_e2[96+ln31];
        f32x16 a0, a1, a2, a3;
        #pragma unroll
        for (int reg = 0; reg < 16; ++reg){ a0[reg]=bz0; a1[reg]=bz1; a2[reg]=bz2; a3[reg]=bz3; }
        gemm4(a0, a1, a2, a3);
        __syncthreads();
        float e0[16], e1v[16], e2v[16], e3[16];
        float sl0=0.f, sh0=0.f, sl1=0.f, sh1=0.f, sl2=0.f, sh2=0.f, sl3=0.f, sh3=0.f;
        #pragma unroll
        for (int reg = 0; reg < 16; ++reg){
            e0[reg]=selu_f(a0[reg]); e1v[reg]=selu_f(a1[reg]);
            e2v[reg]=selu_f(a2[reg]); e3[reg]=selu_f(a3[reg]);
            if (reg < 8){ sl0+=e0[reg]; sl1+=e1v[reg]; sl2+=e2v[reg]; sl3+=e3[reg]; }
            else        { sh0+=e0[reg]; sh1+=e1v[reg]; sh2+=e2v[reg]; sh3+=e3[reg]; }
        }
        sl0 += __shfl_xor(sl0, 32, 64);  sh0 += __shfl_xor(sh0, 32, 64);
        sl1 += __shfl_xor(sl1, 32, 64);  sh1 += __shfl_xor(sh1, 32, 64);
        sl2 += __shfl_xor(sl2, 32, 64);  sh2 += __shfl_xor(sh2, 32, 64);
        sl3 += __shfl_xor(sl3, 32, 64);  sh3 += __shfl_xor(sh3, 32, 64);
        if (grp == 0){
            agg[rt*2+0][ln31]      = sl0;  agg[rt*2+1][ln31]      = sh0;
            agg[rt*2+0][32 + ln31] = sl1;  agg[rt*2+1][32 + ln31] = sh1;
            agg[rt*2+0][64 + ln31] = sl2;  agg[rt*2+1][64 + ln31] = sh2;
            agg[rt*2+0][96 + ln31] = sl3;  agg[rt*2+1][96 + ln31] = sh3;
        }
        #pragma unroll
        for (int reg = 0; reg < 16; ++reg){
            int row = ROW_OF(reg);
            Act[row*SA + ln31]      = (_Float16)e0[reg];
            Act[row*SA + 32 + ln31] = (_Float16)e1v[reg];
            Act[row*SA + 64 + ln31] = (_Float16)e2v[reg];
            Act[row*SA + 96 + ln31] = (_Float16)e3[reg];
        }
        stage_wt(WTg + 2*16384);
        __syncthreads();
    }

    // ================= layer c1 (128 -> 128) + c2 fused =================
    {
        float bz0 = b_c1[ln31],    bz1 = b_c1[32+ln31];
        float bz2 = b_c1[64+ln31], bz3 = b_c1[96+ln31];
        f32x16 a0, a1, a2, a3;
        #pragma unroll
        for (int reg = 0; reg < 16; ++reg){ a0[reg]=bz0; a1[reg]=bz1; a2[reg]=bz2; a3[reg]=bz3; }
        gemm4(a0, a1, a2, a3);
        __syncthreads();
        float wc0 = W_c2[ln31],    wc1 = W_c2[32+ln31];
        float wc2 = W_c2[64+ln31], wc3 = W_c2[96+ln31];
        float bc2 = b_c2[0];
        float p[16];
        #pragma unroll
        for (int reg = 0; reg < 16; ++reg)
            p[reg] = selu_f(a0[reg])*wc0 + selu_f(a1[reg])*wc1
                   + selu_f(a2[reg])*wc2 + selu_f(a3[reg])*wc3;
        #pragma unroll
        for (int msk = 16; msk > 0; msk >>= 1){
            #pragma unroll
            for (int reg = 0; reg < 16; ++reg)
                p[reg] += __shfl_xor(p[reg], msk, 64);
        }
        if (ln31 == 0){
            #pragma unroll
            for (int reg = 0; reg < 16; ++reg)
                wedge[ROW_OF(reg)] = bc2 + p[reg];
        }
        __syncthreads();
    }

    // ================= epilogue: coords, agg writeback =================
    if (tid < 3*NPB){
        int nd = tid / 3, c = tid - nd*3;
        int gi = min(g0 + nd, n - 1);
        float ci = coords[3*gi + c];
        float s = 0.f;
        #pragma unroll
        for (int k = 0; k < KNB; ++k){
            int e = nd*KNB + k;
            s += (ci - coords[3*nb[e] + c]) * wedge[e];
        }
        if (g0 + nd < n) out_coords[3*gi + c] = ci + s * (1.0f/KNB);
    }

    for (int s = tid; s < NPB*192; s += 256){
        int nd = s / 192, c = s - nd*192;
        if (g0 + nd < n){
            float v = (c < HDIM) ? agg[nd][c]
                                 : h[(size_t)j0s[nd]*FDIM + (c - HDIM)];
            aggout[(size_t)(g0 + nd)*192 + c] = v;
        }
    }
}

// ---------------------------------------------------------------------------
// Kernel 3: batched node MLP, fp32. 16 nodes per 256-thread block.
// ---------------------------------------------------------------------------
#define NMB 16
__global__ __launch_bounds__(256) void node_mlp_kernel(
    const float* __restrict__ aggin,
    const float* __restrict__ W_n1, const float* __restrict__ b_n1,
    const float* __restrict__ W_n2, const float* __restrict__ b_n2,
    float* __restrict__ out, int n)
{
    __shared__ __attribute__((aligned(16))) float sinT[192][20];
    __shared__ float part[2][NMB][HDIM];

    const int g0  = blockIdx.x * NMB;
    const int tid = threadIdx.x;
    const int o    = tid & 127;
    const int half = tid >> 7;

    for (int s = tid; s < NMB*192; s += 256){
        size_t gidx = (size_t)g0*192 + s;
        size_t lim  = (size_t)n*192 - 1;
        float v = aggin[gidx < lim ? gidx : lim];
        int nd = s / 192, in = s - nd*192;
        sinT[in][nd] = v;
    }
    __syncthreads();

    {
        float a[NMB];
        #pragma unroll
        for (int d = 0; d < NMB; ++d) a[d] = 0.f;
        int in0 = half * 96;
        for (int in = in0; in < in0 + 96; ++in){
            float w = W_n1[in*HDIM + o];
            const float4* sp = (const float4*)&sinT[in][0];
            float4 v0 = sp[0], v1 = sp[1], v2 = sp[2], v3 = sp[3];
            a[0]  = fmaf(v0.x, w, a[0]);  a[1]  = fmaf(v0.y, w, a[1]);
            a[2]  = fmaf(v0.z, w, a[2]);  a[3]  = fmaf(v0.w, w, a[3]);
            a[4]  = fmaf(v1.x, w, a[4]);  a[5]  = fmaf(v1.y, w, a[5]);
            a[6]  = fmaf(v1.z, w, a[6]);  a[7]  = fmaf(v1.w, w, a[7]);
            a[8]  = fmaf(v2.x, w, a[8]);  a[9]  = fmaf(v2.y, w, a[9]);
            a[10] = fmaf(v2.z, w, a[10]); a[11] = fmaf(v2.w, w, a[11]);
            a[12] = fmaf(v3.x, w, a[12]); a[13] = fmaf(v3.y, w, a[13]);
            a[14] = fmaf(v3.z, w, a[14]); a[15] = fmaf(v3.w, w, a[15]);
        }
        #pragma unroll
        for (int d = 0; d < NMB; ++d) part[half][d][o] = a[d];
    }
    __syncthreads();

    for (int s = tid; s < NMB*HDIM; s += 256){
        int nd = s >> 7, o2 = s & 127;
        sinT[o2][nd] = selu_f(part[0][nd][o2] + part[1][nd][o2] + b_n1[o2]);
    }
    __syncthreads();

    {
        float a[NMB];
        #pragma unroll
        for (int d = 0; d < NMB; ++d) a[d] = 0.f;
        int in0 = half * 64;
        for (int in = in0; in < in0 + 64; ++in){
            float w = W_n2[in*HDIM + o];
            const float4* sp = (const float4*)&sinT[in][0];
            float4 v0 = sp[0], v1 = sp[1], v2 = sp[2], v3 = sp[3];
            a[0]  = fmaf(v0.x, w, a[0]);  a[1]  = fmaf(v0.y, w, a[1]);
            a[2]  = fmaf(v0.z, w, a[2]);  a[3]  = fmaf(v0.w, w, a[3]);
            a[4]  = fmaf(v1.x, w, a[4]);  a[5]  = fmaf(v1.y, w, a[5]);
            a[6]  = fmaf(v1.z, w, a[6]);  a[7]  = fmaf(v1.w, w, a[7]);
            a[8]  = fmaf(v2.x, w, a[8]);  a[9]  = fmaf(v2.y, w, a[9]);
            a[10] = fmaf(v2.z, w, a[10]); a[11] = fmaf(v2.w, w, a[11]);
            a[12] = fmaf(v3.x, w, a[12]); a[13] = fmaf(v3.y, w, a[13]);
            a[14] = fmaf(v3.z, w, a[14]); a[15] = fmaf(v3.w, w, a[15]);
        }
        #pragma unroll
        for (int d = 0; d < NMB; ++d) part[half][d][o] = a[d];
    }
    __syncthreads();

    for (int s = tid; s < NMB*HDIM; s += 256){
        int nd = s >> 7, o2 = s & 127;
        if (g0 + nd < n)
            out[(size_t)(g0 + nd)*HDIM + o2] =
                part[0][nd][o2] + part[1][nd][o2] + b_n2[o2];
    }
}

extern "C" void kernel_launch(void* const* d_in, const int* in_sizes, int n_in,
                              void* d_out, int out_size, void* d_ws, size_t ws_size,
                              hipStream_t stream)
{
    const float* h          = (const float*)d_in[0];
    const float* coords     = (const float*)d_in[1];
    const int*   row_splits = (const int*)  d_in[2];
    const float* W_e1 = (const float*)d_in[3];
    const float* b_e1 = (const float*)d_in[4];
    const float* W_e2 = (const float*)d_in[5];
    const float* b_e2 = (const float*)d_in[6];
    const float* W_c1 = (const float*)d_in[7];
    const float* b_c1 = (const float*)d_in[8];
    const float* W_c2 = (const float*)d_in[9];
    const float* b_c2 = (const float*)d_in[10];
    const float* W_n1 = (const float*)d_in[11];
    const float* b_n1 = (const float*)d_in[12];
    const float* W_n2 = (const float*)d_in[13];
    const float* b_n2 = (const float*)d_in[14];

    const int n    = in_sizes[0] / FDIM;
    const int nseg = in_sizes[2] - 1;

    float* out        = (float*)d_out;
    float* out_coords = out + (size_t)n * HDIM;
    float* out_nidx   = out_coords + (size_t)n * 3;
    float* out_d      = out_nidx + (size_t)n * KNB;

    int*       nidx_i = (int*)d_ws;
    float*     ndist  = (float*)(nidx_i + (size_t)n * KNB);
    int*       idx0   = (int*)(ndist + (size_t)n * KNB);
    _Float16*  WT     = (_Float16*)(idx0 + (size_t)n);       // 3 x 128 x 128 fp16
    float*     aggbuf = (float*)(WT + 3 * 16384);            // n x 192 fp32
    float4*    c4     = (float4*)(aggbuf + (size_t)n * 192); // n x float4

    conv_kernel<<<192, 256, 0, stream>>>(W_e1, W_e2, W_c1, WT);
    pack4_kernel<<<(n + 255) / 256, 256, 0, stream>>>(coords, c4, n);

    knn_kernel<<<(n + 3) / 4, 256, 0, stream>>>(c4, row_splits, nseg, n,
                                                nidx_i, ndist, idx0, out_nidx, out_d);

    egcn_node_kernel<<<(n + NPB - 1) / NPB, 256, 0, stream>>>(
        h, coords, nidx_i, ndist, idx0, WT,
        W_e1, b_e1, b_e2, b_c1, W_c2, b_c2,
        aggbuf, out_coords, n);

    node_mlp_kernel<<<(n + NMB - 1) / NMB, 256, 0, stream>>>(
        aggbuf, W_n1, b_n1, W_n2, b_n2, out, n);
}